// Round 22
// baseline (315.758 us; speedup 1.0000x reference)
//
#include <hip/hip_runtime.h>
#include <math.h>

typedef __bf16 bf16x8 __attribute__((ext_vector_type(8)));
typedef float f32x4 __attribute__((ext_vector_type(4)));
typedef int   i32x4 __attribute__((ext_vector_type(4)));
typedef short short8v __attribute__((ext_vector_type(8)));

#define MARGIN 0.01f
#define NCAND 32

#define WAITL  do { asm volatile("s_waitcnt lgkmcnt(0)" ::: "memory"); __builtin_amdgcn_sched_barrier(0); } while (0)
#define WAITV0 do { asm volatile("s_waitcnt vmcnt(0)" ::: "memory"); __builtin_amdgcn_sched_barrier(0); } while (0)
#define BARR   do { __builtin_amdgcn_s_barrier(); __builtin_amdgcn_sched_barrier(0); } while (0)

__device__ __forceinline__ unsigned short f2bf(float f) {
  unsigned u = __float_as_uint(f);
  u += 0x7fffu + ((u >> 16) & 1u);
  return (unsigned short)(u >> 16);
}
__device__ __forceinline__ float tanh_fast(float x) {
  float e = __builtin_amdgcn_exp2f(x * 2.885390081777927f);
  return 1.f - 2.f * __builtin_amdgcn_rcpf(e + 1.f);
}
__device__ __forceinline__ float exp_fast(float x) {
  return __builtin_amdgcn_exp2f(x * 1.4426950408889634f);
}
// 2 fp32 -> packed 2x bf16 (RNE), single VALU instruction
__device__ __forceinline__ int cvt_pk_bf16(float lo, float hi) {
  int r;
  asm("v_cvt_pk_bf16_f32 %0, %1, %2" : "=v"(r) : "v"(lo), "v"(hi));
  return r;
}
__device__ __forceinline__ void gl_lds16(const void* g, void* l) {
  __builtin_amdgcn_global_load_lds(
      (const __attribute__((address_space(1))) unsigned int*)g,
      (__attribute__((address_space(3))) unsigned int*)l, 16, 0, 0);
}
// DPP row_shr 16-lane reduce; row sum lands in lane 15 (verified R11).
__device__ __forceinline__ float dpp_row_reduce(float v) {
  int x;
  x = __builtin_amdgcn_update_dpp(0, __builtin_bit_cast(int, v), 0x118, 0xf, 0xf, true);
  v += __builtin_bit_cast(float, x);
  x = __builtin_amdgcn_update_dpp(0, __builtin_bit_cast(int, v), 0x114, 0xf, 0xf, true);
  v += __builtin_bit_cast(float, x);
  x = __builtin_amdgcn_update_dpp(0, __builtin_bit_cast(int, v), 0x112, 0xf, 0xf, true);
  v += __builtin_bit_cast(float, x);
  x = __builtin_amdgcn_update_dpp(0, __builtin_bit_cast(int, v), 0x111, 0xf, 0xf, true);
  v += __builtin_bit_cast(float, x);
  return v;
}

// Fused prep. ctx segment: [0,ctx_blocks) fp32->bf16 LINEAR, NT load/store
// (stream-once; avoid L2 write-allocate). Next 512: W-pack. Last 64: inp,
// wave-per-row COALESCED (Wi row held in regs across the 32 batches).
__global__ __launch_bounds__(256) void prep_all_k(
    const float* __restrict__ ctx, const float* __restrict__ x,
    const float* __restrict__ Wi, const float* __restrict__ bi,
    const float* __restrict__ w0, const float* __restrict__ w1,
    const float* __restrict__ w2, const float* __restrict__ w3,
    short* __restrict__ Cbf, short* __restrict__ Whi, float* __restrict__ inp,
    int ctx_blocks) {
  int bid = blockIdx.x;
  if (bid < ctx_blocks) {
    // 33554432 elems = 2 sweeps x 4096 blocks x 256 threads x 16 elems
    const size_t base = ((size_t)bid * 256 + threadIdx.x) * 16;
    #pragma unroll
    for (int it = 0; it < 2; ++it) {
      size_t i = base + (size_t)it * (4096u * 256u * 16u);
      f32x4 f0 = __builtin_nontemporal_load((const f32x4*)(ctx + i));
      f32x4 f1 = __builtin_nontemporal_load((const f32x4*)(ctx + i + 4));
      f32x4 f2 = __builtin_nontemporal_load((const f32x4*)(ctx + i + 8));
      f32x4 f3 = __builtin_nontemporal_load((const f32x4*)(ctx + i + 12));
      i32x4 wA, wB;
      wA.x = cvt_pk_bf16(f0[0], f0[1]); wA.y = cvt_pk_bf16(f0[2], f0[3]);
      wA.z = cvt_pk_bf16(f1[0], f1[1]); wA.w = cvt_pk_bf16(f1[2], f1[3]);
      wB.x = cvt_pk_bf16(f2[0], f2[1]); wB.y = cvt_pk_bf16(f2[2], f2[3]);
      wB.z = cvt_pk_bf16(f3[0], f3[1]); wB.w = cvt_pk_bf16(f3[2], f3[3]);
      __builtin_nontemporal_store(wA, (i32x4*)(Cbf + i));
      __builtin_nontemporal_store(wB, (i32x4*)(Cbf + i + 8));
    }
  } else if (bid < ctx_blocks + 512) {
    int gid = (bid - ctx_blocks) * 256 + threadIdx.x;   // 131072 chunks of 8
    int c = gid & 3, row = (gid >> 2) & 511, TK = gid >> 11;  // TK = TN*16+KS
    int TN = TK >> 4, KS = TK & 15;
    const float* w = (TN == 0) ? w0 : (TN == 1) ? w1 : (TN == 2) ? w2 : w3;
    const float* src = w + (size_t)row * 512 + KS * 32 + c * 8;
    float4 f0 = *(const float4*)(src);
    float4 f1 = *(const float4*)(src + 4);
    int4 wv;
    wv.x = cvt_pk_bf16(f0.x, f0.y); wv.y = cvt_pk_bf16(f0.z, f0.w);
    wv.z = cvt_pk_bf16(f1.x, f1.y); wv.w = cvt_pk_bf16(f1.z, f1.w);
    *(int4*)(Whi + (size_t)gid * 8) = wv;
  } else {
    // inp: 64 blocks = 256 waves; wave -> 2 h-rows x 32 batches, coalesced.
    int bid2 = bid - ctx_blocks - 512;              // 0..63
    int wid = bid2 * 4 + (threadIdx.x >> 6);        // 0..255
    int lane = threadIdx.x & 63;
    #pragma unroll
    for (int hh = 0; hh < 2; ++hh) {
      int h = wid * 2 + hh;                         // 0..511
      f32x4 wv0 = *(const f32x4*)(Wi + (size_t)h * 512 + lane * 8);
      f32x4 wv1 = *(const f32x4*)(Wi + (size_t)h * 512 + lane * 8 + 4);
      float bih = bi[h];
      for (int b2 = 0; b2 < 32; ++b2) {
        f32x4 x0 = *(const f32x4*)(x + b2 * 512 + lane * 8);
        f32x4 x1 = *(const f32x4*)(x + b2 * 512 + lane * 8 + 4);
        float s = wv0[0]*x0[0] + wv0[1]*x0[1] + wv0[2]*x0[2] + wv0[3]*x0[3]
                + wv1[0]*x1[0] + wv1[1]*x1[1] + wv1[2]*x1[2] + wv1[3]*x1[3];
        s = dpp_row_reduce(s);            // lane {15,31,47,63} hold 16-lane sums
        s += __shfl_xor(s, 16, 64);
        s += __shfl_xor(s, 32, 64);
        if (lane == 15) inp[b2 * 512 + h] = bih + s;
      }
    }
  }
}

// GEMM (measured 170 us): 128x512 tile, 16 K-tiles BK=32, 16 waves (2x8),
// per-wave 64x64, 2-slot 80KB ring, drain per tile. stageA: per-lane-gather
// gl_lds from LINEAR bf16 ctx (m173: source per-lane, dst linear).
__global__ __launch_bounds__(1024, 4) void gemm_att_k(
    const short* __restrict__ Cbf, const short* __restrict__ Whi,
    const float* __restrict__ inp,
    const float* __restrict__ bc0, const float* __restrict__ bc1,
    const float* __restrict__ bc2, const float* __restrict__ bc3,
    const float* __restrict__ V, float* __restrict__ att) {
  __shared__ __align__(16) short smem[2][20480];   // 80 KiB: [slot][A4096|B16384]

  const int t = threadIdx.x;
  int d = blockIdx.x + (blockIdx.y << 3);
  int work = (d & 7) * 256 + (d >> 3);           // XCD-contiguous chunks
  int mt = work >> 2, nt = work & 3;             // 4 nt-blocks share mt's A (L2)
  int b = mt >> 4;
  const float* bc = (nt == 0) ? bc0 : (nt == 1) ? bc1 : (nt == 2) ? bc2 : bc3;

  const short* aSrc = Cbf + ((size_t)(mt * 128 + (t >> 2))) * 512 + (t & 3) * 8;
  auto stageA = [&](int tile, int slot) {
    if (t < 512)
      gl_lds16(aSrc + tile * 32, &smem[slot][t * 8]);
  };
  auto stageB = [&](int tile, int slot) {
    const short* gB = Whi + (((size_t)nt * 16 + tile) << 14) + t * 8;
    short* lB = &smem[slot][4096 + t * 8];
    gl_lds16(gB,        lB);
    gl_lds16(gB + 8192, lB + 8192);
  };

  f32x4 acc[4][4];
  #pragma unroll
  for (int i = 0; i < 4; ++i)
    #pragma unroll
    for (int j = 0; j < 4; ++j) acc[i][j] = (f32x4){0.f, 0.f, 0.f, 0.f};

  const int lane = t & 63, wid = t >> 6;         // 16 waves
  const int wr = wid >> 3, wc = wid & 7;         // 2 x 8
  const int fr = lane & 15, fq = lane >> 4;
  const int abase = (wr * 64 + fr) * 32 + fq * 8;          // A: 128 rows
  const int bbase = 4096 + (wc * 64 + fr) * 32 + fq * 8;   // B: 512 rows

  stageA(0, 0); stageB(0, 0);
  WAITV0;
  BARR;

  #pragma unroll 2
  for (int tt = 0; tt < 16; ++tt) {
    const int slot = tt & 1;
    const short* s = &smem[slot][0];
    bf16x8 a[4], bv[4];
    #pragma unroll
    for (int mi = 0; mi < 4; ++mi) a[mi] = *(const bf16x8*)(s + abase + mi * 512);
    #pragma unroll
    for (int ni = 0; ni < 4; ++ni) bv[ni] = *(const bf16x8*)(s + bbase + ni * 512);
    if (tt < 15) { stageA(tt + 1, slot ^ 1); stageB(tt + 1, slot ^ 1); }
    WAITL;
    __builtin_amdgcn_s_setprio(1);
    #pragma unroll
    for (int mi = 0; mi < 4; ++mi)
      #pragma unroll
      for (int ni = 0; ni < 4; ++ni)
        acc[mi][ni] = __builtin_amdgcn_mfma_f32_16x16x32_bf16(a[mi], bv[ni], acc[mi][ni], 0, 0, 0);
    __builtin_amdgcn_s_setprio(0);
    __builtin_amdgcn_sched_barrier(0);
    if (tt < 15) { WAITV0; }
    BARR;
  }

  // epilogue: att[b, nt*2048 + s] += this wave's 64-col partial
  float vV[4], vP[4];
  #pragma unroll
  for (int ni = 0; ni < 4; ++ni) {
    int j = wc * 64 + ni * 16 + fr;
    vV[ni] = V[j];
    vP[ni] = inp[b * 512 + j] + bc[j];
  }
  size_t abatt = (size_t)b * 8192 + (size_t)nt * 2048;
  #pragma unroll
  for (int mi = 0; mi < 4; ++mi) {
    #pragma unroll
    for (int r = 0; r < 4; ++r) {
      float sum = 0.f;
      #pragma unroll
      for (int ni = 0; ni < 4; ++ni)
        sum += vV[ni] * tanh_fast(vP[ni] + acc[mi][ni][r]);
      sum = dpp_row_reduce(sum);
      if (fr == 15) {
        int s2 = (mt & 15) * 128 + wr * 64 + mi * 16 + fq * 4 + r;
        atomicAdd(&att[abatt + s2], sum);
      }
    }
  }
}

// Fallback (tiny ws): direct-fp32-A gemm (reg-staged, T14), from R19.
__global__ __launch_bounds__(1024, 4) void gemm_direct_k(
    const float* __restrict__ ctx, const short* __restrict__ Whi,
    const float* __restrict__ inp,
    const float* __restrict__ bc0, const float* __restrict__ bc1,
    const float* __restrict__ bc2, const float* __restrict__ bc3,
    const float* __restrict__ V, float* __restrict__ att) {
  __shared__ __align__(16) char smem[3][40960];
  const int t = threadIdx.x;
  int d = blockIdx.x + (blockIdx.y << 3);
  int work = (d & 7) * 256 + (d >> 3);
  int mt = work >> 2, nt = work & 3;
  int b = mt >> 4;
  const float* bc = (nt == 0) ? bc0 : (nt == 1) ? bc1 : (nt == 2) ? bc2 : bc3;
  const int ac = t >> 1, ah = t & 1;
  const int ar = ac >> 2, aq = ac & 3;
  const float* aSrc = ctx + ((size_t)mt * 128 + ar) * 512 + aq * 8 + ah * 4;
  const int aDstOff = ar * 32 + aq * 8 + ah * 4;
  auto loadA = [&](int tile) -> float4 { return *(const float4*)(aSrc + tile * 32); };
  auto writeA = [&](const float4& v, int slot) {
    short* dst = (short*)&smem[slot][0] + aDstOff;
    dst[0] = (short)f2bf(v.x); dst[1] = (short)f2bf(v.y);
    dst[2] = (short)f2bf(v.z); dst[3] = (short)f2bf(v.w);
  };
  auto stageB = [&](int tile, int slot) {
    const short* gB = Whi + (((size_t)nt * 16 + tile) << 14) + t * 8;
    short* lB = (short*)&smem[slot][8192] + t * 8;
    gl_lds16(gB, lB);
    gl_lds16(gB + 8192, lB + 8192);
  };
  f32x4 acc[4][4];
  #pragma unroll
  for (int i = 0; i < 4; ++i)
    #pragma unroll
    for (int j = 0; j < 4; ++j) acc[i][j] = (f32x4){0.f, 0.f, 0.f, 0.f};
  const int lane = t & 63, wid = t >> 6;
  const int wr = wid >> 3, wc = wid & 7;
  const int fr = lane & 15, fq = lane >> 4;
  const int abase = (wr * 64 + fr) * 32 + fq * 8;
  const int bbase = 4096 + (wc * 64 + fr) * 32 + fq * 8;
  {
    float4 a0 = loadA(0), a1 = loadA(1);
    stageB(0, 0); stageB(1, 1);
    WAITV0;
    writeA(a0, 0); writeA(a1, 1);
    WAITL;
  }
  BARR;
  for (int tt = 0; tt < 16; ++tt) {
    const int slot = tt % 3;
    const short* As = (const short*)&smem[slot][0];
    float4 anext;
    if (tt < 14) { anext = loadA(tt + 2); stageB(tt + 2, (tt + 2) % 3); }
    bf16x8 a[4], bv[4];
    #pragma unroll
    for (int mi = 0; mi < 4; ++mi) a[mi] = *(const bf16x8*)(As + abase + mi * 512);
    #pragma unroll
    for (int ni = 0; ni < 4; ++ni) bv[ni] = *(const bf16x8*)(As + bbase + ni * 512);
    WAITL;
    #pragma unroll
    for (int mi = 0; mi < 4; ++mi)
      #pragma unroll
      for (int ni = 0; ni < 4; ++ni)
        acc[mi][ni] = __builtin_amdgcn_mfma_f32_16x16x32_bf16(a[mi], bv[ni], acc[mi][ni], 0, 0, 0);
    __builtin_amdgcn_sched_barrier(0);
    if (tt < 14) { WAITV0; writeA(anext, (tt + 2) % 3); }
    BARR;
  }
  float vV[4], vP[4];
  #pragma unroll
  for (int ni = 0; ni < 4; ++ni) {
    int j = wc * 64 + ni * 16 + fr;
    vV[ni] = V[j];
    vP[ni] = inp[b * 512 + j] + bc[j];
  }
  size_t abatt = (size_t)b * 8192 + (size_t)nt * 2048;
  #pragma unroll
  for (int mi = 0; mi < 4; ++mi) {
    #pragma unroll
    for (int r = 0; r < 4; ++r) {
      float sum = 0.f;
      #pragma unroll
      for (int ni = 0; ni < 4; ++ni)
        sum += vV[ni] * tanh_fast(vP[ni] + acc[mi][ni][r]);
      sum = dpp_row_reduce(sum);
      if (fr == 15) {
        int s2 = (mt & 15) * 128 + wr * 64 + mi * 16 + fq * 4 + r;
        atomicAdd(&att[abatt + s2], sum);
      }
    }
  }
}

// Tail (fast-math): max + denom + candidates, fp32 rescore, final outputs.
__global__ __launch_bounds__(1024) void tail_k(const float* __restrict__ att,
    const unsigned char* __restrict__ mask, const float* __restrict__ ctx,
    const float* __restrict__ Wc0, const float* __restrict__ Wc1,
    const float* __restrict__ Wc2, const float* __restrict__ Wc3,
    const float* __restrict__ bc0, const float* __restrict__ bc1,
    const float* __restrict__ bc2, const float* __restrict__ bc3,
    const float* __restrict__ inp, const float* __restrict__ V,
    float* __restrict__ out) {
  int b = blockIdx.x, t = threadIdx.x;
  __shared__ float sred[1024];
  __shared__ float sctx[512];
  __shared__ int scnt;
  __shared__ int scand_j[NCAND];
  __shared__ float scand_a[NCAND];
  __shared__ float sexact[NCAND];

  if (t == 0) scnt = 0;
  float bm = -1e30f;
  for (int j = t; j < 8192; j += 1024) {
    if (mask[b * 2048 + (j & 2047)]) continue;
    bm = fmaxf(bm, att[(size_t)b * 8192 + j]);
  }
  sred[t] = bm;
  __syncthreads();
  for (int s2 = 512; s2 > 0; s2 >>= 1) {
    if (t < s2) sred[t] = fmaxf(sred[t], sred[t + s2]);
    __syncthreads();
  }
  float mx = sred[0];
  float Lref = 10.f * tanh_fast(mx);
  __syncthreads();
  float se = 0.f;
  for (int j = t; j < 8192; j += 1024) {
    if (mask[b * 2048 + (j & 2047)]) continue;
    float a = att[(size_t)b * 8192 + j];
    se += exp_fast(10.f * tanh_fast(a) - Lref);
    if (a >= mx - MARGIN) {
      int slot = atomicAdd(&scnt, 1);
      if (slot < NCAND) { scand_j[slot] = j; scand_a[slot] = a; }
    }
  }
  sred[t] = se;
  __syncthreads();
  for (int s2 = 512; s2 > 0; s2 >>= 1) {
    if (t < s2) sred[t] += sred[t + s2];
    __syncthreads();
  }
  float den = sred[0];
  int n = min(scnt, NCAND);
  for (int j = t; j < 2048; j += 1024)
    out[64 + b * 2048 + j] = mask[b * 2048 + j] ? 1.0f : 0.0f;
  for (int i = 0; i < n; ++i) {
    int jj = scand_j[i];
    int g = jj >> 11, s = jj & 2047;
    const float* W  = (g == 0) ? Wc0 : (g == 1) ? Wc1 : (g == 2) ? Wc2 : Wc3;
    const float* bc = (g == 0) ? bc0 : (g == 1) ? bc1 : (g == 2) ? bc2 : bc3;
    const float* cr = ctx + ((size_t)b * 2048 + s) * 512;
    __syncthreads();
    if (t < 512) sctx[t] = cr[t];
    __syncthreads();
    float total = 0.f;
    if (t < 512) {
      const float* wrp = W + (size_t)t * 512;
      float acc = 0.f;
      #pragma unroll 4
      for (int k = 0; k < 512; k += 4) {
        float4 wv = *(const float4*)(wrp + k);
        acc += wv.x * sctx[k] + wv.y * sctx[k + 1] + wv.z * sctx[k + 2] + wv.w * sctx[k + 3];
      }
      total = V[t] * tanhf(inp[b * 512 + t] + bc[t] + acc);
    }
    sred[t] = total;
    __syncthreads();
    for (int s2 = 512; s2 > 0; s2 >>= 1) {
      if (t < s2) sred[t] += sred[t + s2];
      __syncthreads();
    }
    if (t == 0) sexact[i] = sred[0];
  }
  __syncthreads();
  if (t == 0) {
    float dd = den, best = -1e30f;
    int bj = 0x7fffffff;
    for (int i = 0; i < n; ++i) {
      float e = sexact[i];
      int j = scand_j[i];
      dd += exp_fast(10.f * tanh_fast(e) - Lref) - exp_fast(10.f * tanh_fast(scand_a[i]) - Lref);
      if (e > best || (e == best && j < bj)) { best = e; bj = j; }
    }
    out[b] = (float)bj;
    out[32 + b] = exp_fast(10.f * tanh_fast(best) - Lref) / dd;
  }
}

extern "C" void kernel_launch(void* const* d_in, const int* in_sizes, int n_in,
                              void* d_out, int out_size, void* d_ws, size_t ws_size,
                              hipStream_t stream) {
  const float* x    = (const float*)d_in[0];
  const float* ctx  = (const float*)d_in[1];
  const unsigned char* mask = (const unsigned char*)d_in[2];
  const float* Wi   = (const float*)d_in[3];
  const float* bi   = (const float*)d_in[4];
  const float* Wc0  = (const float*)d_in[5];
  const float* bc0  = (const float*)d_in[6];
  const float* Wc1  = (const float*)d_in[7];
  const float* bc1  = (const float*)d_in[8];
  const float* Wc2  = (const float*)d_in[9];
  const float* bc2  = (const float*)d_in[10];
  const float* Wc3  = (const float*)d_in[11];
  const float* bc3  = (const float*)d_in[12];
  const float* V    = (const float*)d_in[13];
  float* out = (float*)d_out;

  float* inp = (float*)d_ws;             // 16384 f32
  float* att = inp + 16384;              // 262144 f32
  short* Whi = (short*)(att + 262144);   // 1048576 shorts (2 MB)
  short* Cbf = Whi + 1048576;            // 33554432 shorts (64 MB)
  size_t need = (size_t)((char*)(Cbf + 33554432) - (char*)d_ws);
  bool packed = ws_size >= need;

  hipMemsetAsync(att, 0, 262144 * sizeof(float), stream);
  if (packed) {
    prep_all_k<<<4672, 256, 0, stream>>>(ctx, x, Wi, bi,
        Wc0, Wc1, Wc2, Wc3, Cbf, Whi, inp, 4096);
    gemm_att_k<<<dim3(8, 256), 1024, 0, stream>>>(Cbf, Whi,
        inp, bc0, bc1, bc2, bc3, V, att);
  } else {
    prep_all_k<<<576, 256, 0, stream>>>(ctx, x, Wi, bi,
        Wc0, Wc1, Wc2, Wc3, nullptr, Whi, inp, 0);
    gemm_direct_k<<<dim3(8, 256), 1024, 0, stream>>>(ctx, Whi,
        inp, bc0, bc1, bc2, bc3, V, att);
  }
  tail_k<<<32, 1024, 0, stream>>>(att, mask, ctx, Wc0, Wc1, Wc2, Wc3,
      bc0, bc1, bc2, bc3, inp, V, out);
}

// Round 23
// 268.376 us; speedup vs baseline: 1.1765x; 1.1765x over previous
//
#include <hip/hip_runtime.h>
#include <math.h>

typedef __bf16 bf16x8 __attribute__((ext_vector_type(8)));
typedef float f32x4 __attribute__((ext_vector_type(4)));
typedef short short8v __attribute__((ext_vector_type(8)));

#define MARGIN 0.01f
#define NCAND 32

#define WAITL  do { asm volatile("s_waitcnt lgkmcnt(0)" ::: "memory"); __builtin_amdgcn_sched_barrier(0); } while (0)
#define WAITV0 do { asm volatile("s_waitcnt vmcnt(0)" ::: "memory"); __builtin_amdgcn_sched_barrier(0); } while (0)
#define BARR   do { __builtin_amdgcn_s_barrier(); __builtin_amdgcn_sched_barrier(0); } while (0)

__device__ __forceinline__ unsigned short f2bf(float f) {
  unsigned u = __float_as_uint(f);
  u += 0x7fffu + ((u >> 16) & 1u);
  return (unsigned short)(u >> 16);
}
__device__ __forceinline__ float tanh_fast(float x) {
  float e = __builtin_amdgcn_exp2f(x * 2.885390081777927f);
  return 1.f - 2.f * __builtin_amdgcn_rcpf(e + 1.f);
}
__device__ __forceinline__ float exp_fast(float x) {
  return __builtin_amdgcn_exp2f(x * 1.4426950408889634f);
}
__device__ __forceinline__ void gl_lds16(const void* g, void* l) {
  __builtin_amdgcn_global_load_lds(
      (const __attribute__((address_space(1))) unsigned int*)g,
      (__attribute__((address_space(3))) unsigned int*)l, 16, 0, 0);
}
// pack 2 fp32 -> 2 bf16, 1 instruction
__device__ __forceinline__ int cvt_pk_bf16(float lo, float hi) {
  int r;
  asm("v_cvt_pk_bf16_f32 %0, %1, %2" : "=v"(r) : "v"(lo), "v"(hi));
  return r;
}
// DPP row_shr 16-lane reduce; row sum lands in lane 15 (verified R11).
__device__ __forceinline__ float dpp_row_reduce(float v) {
  int x;
  x = __builtin_amdgcn_update_dpp(0, __builtin_bit_cast(int, v), 0x118, 0xf, 0xf, true);
  v += __builtin_bit_cast(float, x);
  x = __builtin_amdgcn_update_dpp(0, __builtin_bit_cast(int, v), 0x114, 0xf, 0xf, true);
  v += __builtin_bit_cast(float, x);
  x = __builtin_amdgcn_update_dpp(0, __builtin_bit_cast(int, v), 0x112, 0xf, 0xf, true);
  v += __builtin_bit_cast(float, x);
  x = __builtin_amdgcn_update_dpp(0, __builtin_bit_cast(int, v), 0x111, 0xf, 0xf, true);
  v += __builtin_bit_cast(float, x);
  return v;
}

// Small prep: blocks [0,512) pack W -> Whi regions (TN 0..3, KS 0..15) of
// 512 rows x 32 k bf16; blocks [512,576) inp.
__global__ __launch_bounds__(256) void prep_small_k(
    const float* __restrict__ x, const float* __restrict__ Wi,
    const float* __restrict__ bi,
    const float* __restrict__ w0, const float* __restrict__ w1,
    const float* __restrict__ w2, const float* __restrict__ w3,
    short* __restrict__ Whi, float* __restrict__ inp) {
  int bid = blockIdx.x;
  if (bid < 512) {
    int gid = bid * 256 + threadIdx.x;   // 131072 chunks of 8
    int c = gid & 3, row = (gid >> 2) & 511, TK = gid >> 11;  // TK = TN*16+KS
    int TN = TK >> 4, KS = TK & 15;
    const float* w = (TN == 0) ? w0 : (TN == 1) ? w1 : (TN == 2) ? w2 : w3;
    const float* src = w + (size_t)row * 512 + KS * 32 + c * 8;
    float f[8];
    *(float4*)&f[0] = *(const float4*)(src);
    *(float4*)&f[4] = *(const float4*)(src + 4);
    short8v hv;
    #pragma unroll
    for (int i = 0; i < 8; ++i) hv[i] = (short)f2bf(f[i]);
    *(short8v*)(Whi + (size_t)gid * 8) = hv;
  } else {
    int gid = (bid - 512) * 256 + threadIdx.x;   // 16384
    int b = gid >> 9, h = gid & 511;
    const float* xr = x + b * 512;
    const float* wr = Wi + h * 512;
    float acc = bi[h];
    #pragma unroll 4
    for (int k = 0; k < 512; k += 4) {
      float4 xv = *(const float4*)(xr + k);
      float4 wv = *(const float4*)(wr + k);
      acc += xv.x * wv.x + xv.y * wv.y + xv.z * wv.z + xv.w * wv.w;
    }
    inp[gid] = acc;
  }
}

// GEMM, BN=512, A direct from fp32 ctx with STAGE-TIME bf16 conversion (T14):
// 128x512 tile, 16 K-tiles BK=32, 16 waves (2wr x 8wc), per-wave 64x64.
// Per tile t: issue A(t+2)->regs + B(t+2) gl_lds BEFORE MFMA; after MFMA
// vmcnt(0) + cvt_pk + ds_write_b64 into slot (t+2)%3 (2-barrier slack).
// 3-slot ring (A bf16 8KB + B 32KB = 40KB/slot, 120KB).
__global__ __launch_bounds__(1024, 4) void gemm_att_k(
    const float* __restrict__ ctx, const short* __restrict__ Whi,
    const float* __restrict__ inp,
    const float* __restrict__ bc0, const float* __restrict__ bc1,
    const float* __restrict__ bc2, const float* __restrict__ bc3,
    const float* __restrict__ V, float* __restrict__ att) {
  __shared__ __align__(16) char smem[3][40960];   // [slot][A bf16 8K | B bf16 32K]

  const int t = threadIdx.x;
  int d = blockIdx.x + (blockIdx.y << 3);
  int work = (d & 7) * 256 + (d >> 3);           // XCD-contiguous chunks
  int mt = work >> 2, nt = work & 3;             // 4 nt-blocks share mt's A (L2)
  int b = mt >> 4;
  const float* bc = (nt == 0) ? bc0 : (nt == 1) ? bc1 : (nt == 2) ? bc2 : bc3;

  // A staging coords: thread t -> chunk c=t>>1 (of 512), half h=t&1.
  // row r=c>>2, 16B-chunk q=c&3. fp32 float4 -> 4 bf16 (8B ds_write_b64).
  const int ac = t >> 1, ah = t & 1;
  const int ar = ac >> 2, aq = ac & 3;
  const float* aSrc = ctx + ((size_t)mt * 128 + ar) * 512 + aq * 8 + ah * 4;
  const int aDstOff = ar * 32 + aq * 8 + ah * 4;         // shorts

  auto loadA = [&](int tile) -> float4 { return *(const float4*)(aSrc + tile * 32); };
  auto writeA = [&](const float4& v, int slot) {
    int2 w;
    w.x = cvt_pk_bf16(v.x, v.y);
    w.y = cvt_pk_bf16(v.z, v.w);
    *(int2*)((short*)&smem[slot][0] + aDstOff) = w;
  };
  auto stageB = [&](int tile, int slot) {
    const short* gB = Whi + (((size_t)nt * 16 + tile) << 14) + t * 8;
    short* lB = (short*)&smem[slot][8192] + t * 8;
    gl_lds16(gB,        lB);
    gl_lds16(gB + 8192, lB + 8192);
  };

  f32x4 acc[4][4];
  #pragma unroll
  for (int i = 0; i < 4; ++i)
    #pragma unroll
    for (int j = 0; j < 4; ++j) acc[i][j] = (f32x4){0.f, 0.f, 0.f, 0.f};

  const int lane = t & 63, wid = t >> 6;         // 16 waves
  const int wr = wid >> 3, wc = wid & 7;         // 2 x 8
  const int fr = lane & 15, fq = lane >> 4;
  const int abase = (wr * 64 + fr) * 32 + fq * 8;          // shorts, 128-row A
  const int bbase = 8192 / 2 + (wc * 64 + fr) * 32 + fq * 8;  // shorts from slot base

  // prologue: tiles 0,1
  {
    float4 a0 = loadA(0), a1 = loadA(1);
    stageB(0, 0); stageB(1, 1);
    WAITV0;
    writeA(a0, 0); writeA(a1, 1);
    WAITL;
  }
  BARR;

  #pragma unroll
  for (int tt = 0; tt < 16; ++tt) {
    const int slot = tt % 3;
    const short* As = (const short*)&smem[slot][0];
    float4 anext;
    if (tt < 14) { anext = loadA(tt + 2); stageB(tt + 2, (tt + 2) % 3); }
    bf16x8 a[4], bv[4];
    #pragma unroll
    for (int mi = 0; mi < 4; ++mi) a[mi] = *(const bf16x8*)(As + abase + mi * 512);
    #pragma unroll
    for (int ni = 0; ni < 4; ++ni) bv[ni] = *(const bf16x8*)(As + bbase + ni * 512);
    WAITL;
    __builtin_amdgcn_s_setprio(1);
    #pragma unroll
    for (int mi = 0; mi < 4; ++mi)
      #pragma unroll
      for (int ni = 0; ni < 4; ++ni)
        acc[mi][ni] = __builtin_amdgcn_mfma_f32_16x16x32_bf16(a[mi], bv[ni], acc[mi][ni], 0, 0, 0);
    __builtin_amdgcn_s_setprio(0);
    __builtin_amdgcn_sched_barrier(0);
    if (tt < 14) {
      WAITV0;                        // anext + B(t+2) landed under MFMA
      writeA(anext, (tt + 2) % 3);   // write-late; drained by next tile's WAITL
    }
    BARR;
  }

  // epilogue: att[b, nt*2048 + s] += this wave's 64-col partial
  float vV[4], vP[4];
  #pragma unroll
  for (int ni = 0; ni < 4; ++ni) {
    int j = wc * 64 + ni * 16 + fr;
    vV[ni] = V[j];
    vP[ni] = inp[b * 512 + j] + bc[j];
  }
  size_t abatt = (size_t)b * 8192 + (size_t)nt * 2048;
  #pragma unroll
  for (int mi = 0; mi < 4; ++mi) {
    #pragma unroll
    for (int r = 0; r < 4; ++r) {
      float sum = 0.f;
      #pragma unroll
      for (int ni = 0; ni < 4; ++ni)
        sum += vV[ni] * tanh_fast(vP[ni] + acc[mi][ni][r]);
      sum = dpp_row_reduce(sum);
      if (fr == 15) {
        int s2 = (mt & 15) * 128 + wr * 64 + mi * 16 + fq * 4 + r;
        atomicAdd(&att[abatt + s2], sum);
      }
    }
  }
}

// Tail (fast-math): max + denom + candidates, fp32 rescore, final outputs.
__global__ __launch_bounds__(1024) void tail_k(const float* __restrict__ att,
    const unsigned char* __restrict__ mask, const float* __restrict__ ctx,
    const float* __restrict__ Wc0, const float* __restrict__ Wc1,
    const float* __restrict__ Wc2, const float* __restrict__ Wc3,
    const float* __restrict__ bc0, const float* __restrict__ bc1,
    const float* __restrict__ bc2, const float* __restrict__ bc3,
    const float* __restrict__ inp, const float* __restrict__ V,
    float* __restrict__ out) {
  int b = blockIdx.x, t = threadIdx.x;
  __shared__ float sred[1024];
  __shared__ float sctx[512];
  __shared__ int scnt;
  __shared__ int scand_j[NCAND];
  __shared__ float scand_a[NCAND];
  __shared__ float sexact[NCAND];

  if (t == 0) scnt = 0;
  float bm = -1e30f;
  for (int j = t; j < 8192; j += 1024) {
    if (mask[b * 2048 + (j & 2047)]) continue;
    bm = fmaxf(bm, att[(size_t)b * 8192 + j]);
  }
  sred[t] = bm;
  __syncthreads();
  for (int s2 = 512; s2 > 0; s2 >>= 1) {
    if (t < s2) sred[t] = fmaxf(sred[t], sred[t + s2]);
    __syncthreads();
  }
  float mx = sred[0];
  float Lref = 10.f * tanh_fast(mx);
  __syncthreads();
  float se = 0.f;
  for (int j = t; j < 8192; j += 1024) {
    if (mask[b * 2048 + (j & 2047)]) continue;
    float a = att[(size_t)b * 8192 + j];
    se += exp_fast(10.f * tanh_fast(a) - Lref);
    if (a >= mx - MARGIN) {
      int slot = atomicAdd(&scnt, 1);
      if (slot < NCAND) { scand_j[slot] = j; scand_a[slot] = a; }
    }
  }
  sred[t] = se;
  __syncthreads();
  for (int s2 = 512; s2 > 0; s2 >>= 1) {
    if (t < s2) sred[t] += sred[t + s2];
    __syncthreads();
  }
  float den = sred[0];
  int n = min(scnt, NCAND);
  for (int j = t; j < 2048; j += 1024)
    out[64 + b * 2048 + j] = mask[b * 2048 + j] ? 1.0f : 0.0f;
  for (int i = 0; i < n; ++i) {
    int jj = scand_j[i];
    int g = jj >> 11, s = jj & 2047;
    const float* W  = (g == 0) ? Wc0 : (g == 1) ? Wc1 : (g == 2) ? Wc2 : Wc3;
    const float* bc = (g == 0) ? bc0 : (g == 1) ? bc1 : (g == 2) ? bc2 : bc3;
    const float* cr = ctx + ((size_t)b * 2048 + s) * 512;
    __syncthreads();
    if (t < 512) sctx[t] = cr[t];
    __syncthreads();
    float total = 0.f;
    if (t < 512) {
      const float* wrp = W + (size_t)t * 512;
      float acc = 0.f;
      #pragma unroll 4
      for (int k = 0; k < 512; k += 4) {
        float4 wv = *(const float4*)(wrp + k);
        acc += wv.x * sctx[k] + wv.y * sctx[k + 1] + wv.z * sctx[k + 2] + wv.w * sctx[k + 3];
      }
      total = V[t] * tanhf(inp[b * 512 + t] + bc[t] + acc);
    }
    sred[t] = total;
    __syncthreads();
    for (int s2 = 512; s2 > 0; s2 >>= 1) {
      if (t < s2) sred[t] += sred[t + s2];
      __syncthreads();
    }
    if (t == 0) sexact[i] = sred[0];
  }
  __syncthreads();
  if (t == 0) {
    float dd = den, best = -1e30f;
    int bj = 0x7fffffff;
    for (int i = 0; i < n; ++i) {
      float e = sexact[i];
      int j = scand_j[i];
      dd += exp_fast(10.f * tanh_fast(e) - Lref) - exp_fast(10.f * tanh_fast(scand_a[i]) - Lref);
      if (e > best || (e == best && j < bj)) { best = e; bj = j; }
    }
    out[b] = (float)bj;
    out[32 + b] = exp_fast(10.f * tanh_fast(best) - Lref) / dd;
  }
}

extern "C" void kernel_launch(void* const* d_in, const int* in_sizes, int n_in,
                              void* d_out, int out_size, void* d_ws, size_t ws_size,
                              hipStream_t stream) {
  const float* x    = (const float*)d_in[0];
  const float* ctx  = (const float*)d_in[1];
  const unsigned char* mask = (const unsigned char*)d_in[2];
  const float* Wi   = (const float*)d_in[3];
  const float* bi   = (const float*)d_in[4];
  const float* Wc0  = (const float*)d_in[5];
  const float* bc0  = (const float*)d_in[6];
  const float* Wc1  = (const float*)d_in[7];
  const float* bc1  = (const float*)d_in[8];
  const float* Wc2  = (const float*)d_in[9];
  const float* bc2  = (const float*)d_in[10];
  const float* Wc3  = (const float*)d_in[11];
  const float* bc3  = (const float*)d_in[12];
  const float* V    = (const float*)d_in[13];
  float* out = (float*)d_out;

  float* inp = (float*)d_ws;             // 16384 f32
  float* att = inp + 16384;              // 262144 f32
  short* Whi = (short*)(att + 262144);   // 1048576 shorts (2 MB)

  hipMemsetAsync(att, 0, 262144 * sizeof(float), stream);
  prep_small_k<<<576, 256, 0, stream>>>(x, Wi, bi, Wc0, Wc1, Wc2, Wc3, Whi, inp);
  gemm_att_k<<<dim3(8, 256), 1024, 0, stream>>>(ctx, Whi,
      inp, bc0, bc1, bc2, bc3, V, att);
  tail_k<<<32, 1024, 0, stream>>>(att, mask, ctx, Wc0, Wc1, Wc2, Wc3,
      bc0, bc1, bc2, bc3, inp, V, out);
}